// Round 10
// baseline (9371.440 us; speedup 1.0000x reference)
//
#include <hip/hip_runtime.h>
#include <cstdint>

typedef _Float16 f16;
typedef _Float16 f16x8 __attribute__((ext_vector_type(8)));
typedef float    f32x4 __attribute__((ext_vector_type(4)));

#define DINL __device__ __forceinline__

static constexpr int HID = 1024;
static constexpr int NG  = 4096;   // 4*HID gate count
static constexpr int BB  = 256;    // batch
static constexpr int TT  = 100;    // seq len
static constexpr int KX  = 256;    // padded input-feature K (227 -> 256)
static constexpr size_t MSZ = (size_t)NG * HID;   // halves per packed [4096][1024] mat

// ---- workspace layout (bytes). total ~124 MiB ----
static constexpr size_t OFF_PACKW5 = 0;
static constexpr size_t OFF_W1D    = OFF_PACKW5 + 5*MSZ*2;
static constexpr size_t OFF_WIH1   = OFF_W1D   + MSZ*2;
static constexpr size_t OFF_WD     = OFF_WIH1  + (size_t)NG*KX*2;
static constexpr size_t OFF_XPAD   = OFF_WD    + (size_t)256*HID*2;
static constexpr size_t OFF_BIAS   = OFF_XPAD  + (size_t)TT*BB*KX*2;
static constexpr size_t OFF_C      = OFF_BIAS  + (size_t)4*NG*4;   // arrive flags (C in regs)
static constexpr size_t OFF_HBUF   = OFF_C     + (size_t)3*BB*HID*4;
static constexpr size_t OFF_H2Z    = OFF_HBUF  + (size_t)4*BB*HID*2;
static constexpr size_t OFF_H2ALL  = OFF_H2Z   + (size_t)BB*HID*2;
// WdT scratch (frag-packed [1024 n][256 k] f16) lives at OFF_H2ALL until k_w1d consumes it.

// Fragment-packed layout ("frag order") for a [n][k] matrix, NCH = K/64:
// unit (nt=n>>4, c=k>>6, kw=(k>>5)&1) = 1KB; lane l=(n&15)|(quad<<4) holds the
// 8 f16 at k = c*64+kw*32+quad*8+e. A wave's fragment = ONE 1KB load at base+lane*16.
DINL size_t fpo(int n, int k, int NCH){
  return ((((size_t)(n>>4)*NCH + (k>>6))*2 + ((k>>5)&1)) << 9)
       + ((size_t)((n&15) | (((k>>3)&3) << 4)) << 3) + (k&7);
}

DINL void async16(void* lds, const void* g){
  auto lp = reinterpret_cast<__attribute__((address_space(3))) unsigned int*>(
      reinterpret_cast<uintptr_t>(lds));
  auto gp = reinterpret_cast<const __attribute__((address_space(1))) unsigned int*>(
      reinterpret_cast<uintptr_t>(g));
  __builtin_amdgcn_global_load_lds(gp, lp, 16, 0, 0);
}

// LDS read via inline asm: invisible to the compiler's LDS-DMA waitcnt pass.
DINL f16x8 ldsr128(unsigned a){
  f16x8 r;
  asm volatile("ds_read_b128 %0, %1" : "=v"(r) : "v"(a));
  return r;
}

// coalesced global->VGPR fragment load, 64-bit vaddr form
DINL f16x8 gload(const void* addr){
  f16x8 r;
  asm volatile("global_load_dwordx4 %0, %1, off"
    : "=v"(r) : "v"(addr));
  return r;
}

DINL f32x4 mfma8(f16x8 a, f16x8 b, f32x4 c){
  return __builtin_amdgcn_mfma_f32_16x16x32_f16(a, b, c, 0, 0, 0);
}

DINL float sigf(float x){
  x = fminf(fmaxf(x, -30.f), 30.f);
  return __fdividef(1.f, 1.f + __expf(-x));
}
DINL float tanh_fast(float x){
  x = fminf(fmaxf(x, -15.f), 15.f);
  float t = __expf(2.f*x);
  return __fdividef(t - 1.f, t + 1.f);
}

// ================= prep kernels (all weights + activations FRAG-PACKED) =================

__global__ void k_pack5(const float* W0, const float* W1, const float* W2,
                        const float* W3, const float* W4, char* ws)
{
  f16* dst = (f16*)(ws + OFF_PACKW5);
  const int mat = blockIdx.y;
  const float* src = mat==0?W0 : mat==1?W1 : mat==2?W2 : mat==3?W3 : W4;
  int tid = blockIdx.x*256 + threadIdx.x;
  int n = tid >> 7, kc = tid & 127;
  int r = ((n&3) << 10) + (n >> 2);
  const float* s = src + (size_t)r*HID + kc*8;
  f16x8 o;
  #pragma unroll
  for (int i = 0; i < 8; i++) o[i] = (f16)s[i];
  int nt = n >> 4, cch = kc >> 3, kw = (kc >> 2) & 1, quad = kc & 3;
  size_t off = ((((size_t)nt*16 + cch)*2 + kw) << 9)
             + ((size_t)((n&15) | (quad<<4)) << 3);
  *(f16x8*)(dst + (size_t)mat*MSZ + off) = o;
}

__global__ void k_packwih1(const float* __restrict__ Wih1, char* ws){
  f16* dst = (f16*)(ws + OFF_WIH1);           // frag-packed, NCH=4
  int n = blockIdx.x, k = threadIdx.x;
  int r = ((n&3) << 10) + (n >> 2);
  dst[fpo(n, k, 4)] = (k < 227) ? (f16)Wih1[(size_t)r*227 + k] : (f16)0.f;
}

__global__ void k_packwd(const float* __restrict__ Wd, char* ws){
  f16* dst = (f16*)(ws + OFF_WD);             // frag-packed [256 o][1024 h], NCH=16
  int idx = blockIdx.x*256 + threadIdx.x;
  int o = idx >> 7, k8 = idx & 127;
  f16x8 v;
  #pragma unroll
  for (int e = 0; e < 8; e++)
    v[e] = (o < 227) ? (f16)Wd[(size_t)o*HID + k8*8 + e] : (f16)0.f;
  size_t off = ((((size_t)(o>>4)*16 + (k8>>3))*2 + ((k8>>2)&1)) << 9)
             + ((size_t)((o&15) | ((k8&3)<<4)) << 3);
  *(f16x8*)(dst + off) = v;
}

__global__ void k_packwdt(const float* __restrict__ Wd, char* ws){
  f16* dst = (f16*)(ws + OFF_H2ALL);          // WdT frag-packed, n=h, k=o, NCH=4
  int h = blockIdx.x, o = threadIdx.x;
  dst[fpo(h, o, 4)] = (o < 227) ? (f16)Wd[(size_t)o*HID + h] : (f16)0.f;
}

__global__ void k_xpad(const float* __restrict__ seq, char* ws){
  f16* dst = (f16*)(ws + OFF_XPAD);           // per-t frag-packed [256 b][256 k], NCH=4
  int idx = blockIdx.x*256 + threadIdx.x;
  int t = idx >> 13, rem = idx & 8191, b = rem >> 5, k8 = rem & 31;
  f16x8 v;
  #pragma unroll
  for (int e = 0; e < 8; e++){
    int k = k8*8 + e;
    v[e] = (k < 227) ? (f16)seq[(size_t)b*22700 + (size_t)t*227 + k] : (f16)0.f;
  }
  size_t off = ((((size_t)(b>>4)*4 + (k8>>3))*2 + ((k8>>2)&1)) << 9)
             + ((size_t)((b&15) | ((k8&3)<<4)) << 3);
  *(f16x8*)(dst + (size_t)t*BB*KX + off) = v;
}

__global__ void k_bias(const float* bih1, const float* bhh1, const float* bih2, const float* bhh2,
                       const float* bih3, const float* bhh3, const float* Wih1, const float* bd,
                       char* ws)
{
  int n = blockIdx.x*256 + threadIdx.x;
  if (n >= NG) return;
  int r = ((n&3) << 10) + (n >> 2);
  float* b = (float*)(ws + OFF_BIAS);
  float bf = bih1[r] + bhh1[r];
  float s = 0.f;
  for (int o = 0; o < 227; o++) s += Wih1[(size_t)r*227 + o] * bd[o];
  b[n]        = bf;
  b[NG + n]   = bf + s;
  b[2*NG + n] = bih2[r] + bhh2[r];
  b[3*NG + n] = bih3[r] + bhh3[r];
}

// W1D = WIH1(frag,NCH=4) @ WdT(frag,NCH=4) -> frag-packed (NCH=16) output. LDS-free.
__global__ __launch_bounds__(256) void k_w1d(char* ws)
{
  const int w = threadIdx.x >> 6, lane = threadIdx.x & 63;
  const int n0 = blockIdx.x*128, m0 = blockIdx.y*128;
  const f16* Af = (const f16*)(ws + OFF_WIH1);
  const f16* Bf = (const f16*)(ws + OFF_H2ALL);
  f16* W1D = (f16*)(ws + OFF_W1D);
  const int m_w = m0 + (w>>1)*64, n_w = n0 + (w&1)*64;
  const int vl = lane*8;

  f32x4 acc[4][4];
  f32x4 zero = {0.f, 0.f, 0.f, 0.f};
  #pragma unroll
  for (int i = 0; i < 4; i++)
    #pragma unroll
    for (int j = 0; j < 4; j++) acc[i][j] = zero;

  for (int c = 0; c < 4; c++){
    f16x8 av[4][2], bv[4][2];
    #pragma unroll
    for (int ti = 0; ti < 4; ti++)
      #pragma unroll
      for (int kw = 0; kw < 2; kw++)
        av[ti][kw] = *(const f16x8*)(Af + ((((size_t)((m_w>>4)+ti)*4 + c)*2 + kw) << 9) + vl);
    #pragma unroll
    for (int tj = 0; tj < 4; tj++)
      #pragma unroll
      for (int kw = 0; kw < 2; kw++)
        bv[tj][kw] = *(const f16x8*)(Bf + ((((size_t)((n_w>>4)+tj)*4 + c)*2 + kw) << 9) + vl);
    #pragma unroll
    for (int kw = 0; kw < 2; kw++)
      #pragma unroll
      for (int ti = 0; ti < 4; ti++)
        #pragma unroll
        for (int tj = 0; tj < 4; tj++)
          acc[ti][tj] = mfma8(av[ti][kw], bv[tj][kw], acc[ti][tj]);
  }

  const int quad = lane>>4, c15 = lane&15;
  #pragma unroll
  for (int tj = 0; tj < 4; tj++){
    int col = n_w + tj*16 + c15;
    #pragma unroll
    for (int ti = 0; ti < 4; ti++){
      f32x4 v = acc[ti][tj];
      #pragma unroll
      for (int r = 0; r < 4; r++){
        int m = m_w + ti*16 + quad*4 + r;
        W1D[fpo(m, col, 16)] = (f16)v[r];
      }
    }
  }
}

// ================= persistent recurrent kernel =================
// 192 blocks (64 ntiles, 3 layers) co-resident (cooperative launch, NO grid.sync).
// Per step: round-8 K-loop body verbatim. Cross-step sync: per-layer arrival
// counters + __threadfence release/acquire (deps incl. WAR on ping-pong h slots):
//   L0: arr0, arr1, (arr2 if !use_gt);  L1: arr0, arr1, arr2;  L2: arr1, arr2.
// Next-step B groups 0,1 (t-invariant weights) prefetched BEFORE the sync window.
// C-state and biases live in registers for the whole sequence.
__global__ __launch_bounds__(512, 1) void k_steps(char* __restrict__ ws)
{
  __shared__ __align__(16) char lds[65536];
  const int w = threadIdx.x >> 6, lane = threadIdx.x & 63;
  const int col0 = blockIdx.x*64, layer = blockIdx.y;

  const f16* packW = (const f16*)(ws + OFF_PACKW5);
  const f16* W1D   = (const f16*)(ws + OFF_W1D);
  const f16* WIH1  = (const f16*)(ws + OFF_WIH1);
  const f16* XPb   = (const f16*)(ws + OFF_XPAD);
  const float* biasb = (const float*)(ws + OFF_BIAS);
  unsigned* arrive = (unsigned*)(ws + OFF_C);   // [layer*32], zeroed by host memset
  f16* HB  = (f16*)(ws + OFF_HBUF);
  f16* H2Z = (f16*)(ws + OFF_H2Z);
  f16* H2A = (f16*)(ws + OFF_H2ALL);

  // t-invariant per-layer weights
  const f16* B0  = (layer==0) ? packW : (layer==1) ? packW + MSZ : packW + 3*MSZ;
  const f16* B1n = (layer==0) ? W1D   : (layer==1) ? packW + 2*MSZ : packW + 4*MSZ; // non-gt mat1 (NCH=16)

  const int m_w = w*32, c15 = lane&15, quad = lane>>4;
  const unsigned vl16 = (unsigned)(lane * 16);
  const unsigned ldsBase = (unsigned)(uintptr_t)lds;

  // B unit bases for THIS wave's piece (tj=w>>1, kw=w&1)
  const char* b0u   = (const char*)B0  + (size_t)((col0>>4) + (w>>1))*16*2048 + (size_t)(w&1)*1024 + (size_t)lane*16;
  const char* b1u_n = (const char*)B1n + (size_t)((col0>>4) + (w>>1))*16*2048 + (size_t)(w&1)*1024 + (size_t)lane*16;
  const char* b1u_g = (const char*)WIH1 + (size_t)((col0>>4) + (w>>1))*4*2048 + (size_t)(w&1)*1024 + (size_t)lane*16; // layer0-gt

  // bias preload (layer0: two variants)
  const float* bsel0 = (layer==0) ? biasb      : (layer==1) ? biasb + 2*NG : biasb + 3*NG;
  const float* bsel1 = (layer==0) ? biasb + NG : bsel0;
  float bgt[4], bngt[4];
  #pragma unroll
  for (int tj = 0; tj < 4; tj++){
    int ncol = col0 + tj*16 + c15;
    bgt[tj]  = bsel0[ncol];
    bngt[tj] = bsel1[ncol];
  }

  // C state in registers for the whole sequence
  float creg[32];
  #pragma unroll
  for (int i = 0; i < 32; i++) creg[i] = 0.f;

  f32x4 zero = {0.f, 0.f, 0.f, 0.f};
  f16x8 A0r[4], A1r[4], A2r[4];   // three A banks (chunk%3), idx = ti*2+kw
  f16x8 F0[8], F1[8];             // two B frag banks (chunk&1), idx = tj*2+kw

  auto prefetchB01 = [&](){       // chunks 0..7 of B0 (t-invariant), slabs 0..7
    #pragma unroll
    for (int k = 0; k < 8; k++)
      async16(lds + k*8192 + w*1024, b0u + (size_t)k*2048);
  };

  prefetchB01();                  // for t=0

  for (int t = 0; t < TT; ++t){
    const int use_gt = ((t % 10) < 5) ? 1 : 0;
    const int pr = t & 1, pw = pr ^ 1;
    const f16* h0p = HB + (size_t)(pr*2 + 0)*BB*HID;
    const f16* h1p = HB + (size_t)(pr*2 + 1)*BB*HID;
    const f16* h2p = (t == 0) ? H2Z : (H2A + (size_t)(t-1)*BB*HID);

    const f16 *A0, *A1; const char* b1u; int NCH1; f16* hout;
    if (layer == 0){
      A0 = h0p;
      if (use_gt){ A1 = XPb + (size_t)t*BB*KX; b1u = b1u_g; NCH1 = 4;  }
      else       { A1 = h2p;                   b1u = b1u_n; NCH1 = 16; }
      hout = HB + (size_t)(pw*2 + 0)*BB*HID;
    } else if (layer == 1){
      A0 = h0p; A1 = h1p; b1u = b1u_n; NCH1 = 16;
      hout = HB + (size_t)(pw*2 + 1)*BB*HID;
    } else {
      A0 = h1p; A1 = h2p; b1u = b1u_n; NCH1 = 16;
      hout = H2A + (size_t)t*BB*HID;
    }
    const int ncmax = 16 + NCH1;          // 32, or 20 for layer0/gt  (r9 bug: was 44)
    const int nblk  = (ncmax - 8) / 12;   // 2 or 1

    // ---- sync: wait for step t-1 producers (and WAR readers) ----
    if (t > 0){
      const unsigned needv = 64u * (unsigned)t;
      if (threadIdx.x < 3){
        const int idx = threadIdx.x;
        bool req = (layer == 0) ? (idx < 2 || !use_gt)
                 : (layer == 1) ? true : (idx >= 1);
        if (req){
          while (__hip_atomic_load(&arrive[idx*32], __ATOMIC_RELAXED,
                                   __HIP_MEMORY_SCOPE_AGENT) < needv)
            __builtin_amdgcn_s_sleep(2);
        }
      }
      __syncthreads();
      __threadfence();              // acquire: drains prefetch DMAs + invalidates stale lines
    }

    // A per-lane unit bases per row-tile ti
    const char* a0b[2]; const char* a1b[2];
    #pragma unroll
    for (int ti = 0; ti < 2; ti++){
      a0b[ti] = (const char*)A0 + (size_t)(2*w + ti)*16*2048   + (size_t)lane*16;
      a1b[ti] = (const char*)A1 + (size_t)(2*w + ti)*NCH1*2048 + (size_t)lane*16;
    }
    auto issueB = [&](int ci){
      const char* s = (ci < 16) ? (b0u + (size_t)ci*2048) : (b1u + (size_t)(ci-16)*2048);
      async16(lds + (ci & 7)*8192 + w*1024, s);
    };
    auto abase = [&](int ci, int ti)->const char*{
      return (ci < 16) ? (a0b[ti] + (size_t)ci*2048) : (a1b[ti] + (size_t)(ci-16)*2048);
    };

    f32x4 acc[2][4];
    #pragma unroll
    for (int i = 0; i < 2; i++)
      #pragma unroll
      for (int j = 0; j < 4; j++) acc[i][j] = zero;

#define ISSUEA(CI, AK)                                           \
  { const char* _b0 = abase((CI), 0);                            \
    const char* _b1 = abase((CI), 1);                            \
    AK[0] = gload(_b0);                                          \
    AK[1] = gload(_b0 + 1024);                                   \
    AK[2] = gload(_b1);                                          \
    AK[3] = gload(_b1 + 1024); }

#define WAITA_N(LIT, AK) asm volatile("s_waitcnt vmcnt(" #LIT ")" \
    : "+v"(AK[0]), "+v"(AK[1]), "+v"(AK[2]), "+v"(AK[3]))

#define DS8(CI, F)                                               \
  { const unsigned _sb = ldsBase + (unsigned)(((CI)&7)*8192) + vl16; \
    F[0] = ldsr128(_sb);         F[1] = ldsr128(_sb + 1024u);    \
    F[2] = ldsr128(_sb + 2048u); F[3] = ldsr128(_sb + 3072u);    \
    F[4] = ldsr128(_sb + 4096u); F[5] = ldsr128(_sb + 5120u);    \
    F[6] = ldsr128(_sb + 6144u); F[7] = ldsr128(_sb + 7168u); }

#define LGKM_N(LIT, F) asm volatile("s_waitcnt lgkmcnt(" #LIT ")" \
    : "+v"(F[0]), "+v"(F[1]), "+v"(F[2]), "+v"(F[3]),            \
      "+v"(F[4]), "+v"(F[5]), "+v"(F[6]), "+v"(F[7]))

#define MFMA16(AK, F)                                            \
    acc[0][0] = mfma8(AK[0], F[0], acc[0][0]);                   \
    acc[0][1] = mfma8(AK[0], F[2], acc[0][1]);                   \
    acc[0][2] = mfma8(AK[0], F[4], acc[0][2]);                   \
    acc[0][3] = mfma8(AK[0], F[6], acc[0][3]);                   \
    acc[1][0] = mfma8(AK[2], F[0], acc[1][0]);                   \
    acc[1][1] = mfma8(AK[2], F[2], acc[1][1]);                   \
    acc[1][2] = mfma8(AK[2], F[4], acc[1][2]);                   \
    acc[1][3] = mfma8(AK[2], F[6], acc[1][3]);                   \
    acc[0][0] = mfma8(AK[1], F[1], acc[0][0]);                   \
    acc[0][1] = mfma8(AK[1], F[3], acc[0][1]);                   \
    acc[0][2] = mfma8(AK[1], F[5], acc[0][2]);                   \
    acc[0][3] = mfma8(AK[1], F[7], acc[0][3]);                   \
    acc[1][0] = mfma8(AK[3], F[1], acc[1][0]);                   \
    acc[1][1] = mfma8(AK[3], F[3], acc[1][1]);                   \
    acc[1][2] = mfma8(AK[3], F[5], acc[1][2]);                   \
    acc[1][3] = mfma8(AK[3], F[7], acc[1][3]);

#define BARRIER_ { __builtin_amdgcn_s_barrier(); __builtin_amdgcn_sched_barrier(0); }
#define ISSUEB4(G) { const int _cb = 4*(G); issueB(_cb); issueB(_cb+1); issueB(_cb+2); issueB(_cb+3); }

    // ---- body (round-8 schedule; B groups 0,1 already prefetched) ----
    ISSUEA(0, A0r); ISSUEA(1, A1r); ISSUEA(2, A2r);
    asm volatile("s_waitcnt vmcnt(16)" ::: "memory");
    BARRIER_;
    DS8(0, F0);

    WAITA_N(8, A0r); DS8(1, F1); LGKM_N(8, F0); MFMA16(A0r, F0); ISSUEA(3, A0r);
    WAITA_N(8, A1r); DS8(2, F0); LGKM_N(8, F1); MFMA16(A1r, F1); ISSUEA(4, A1r);
    WAITA_N(8, A2r); DS8(3, F1); LGKM_N(8, F0); MFMA16(A2r, F0); ISSUEA(5, A2r);

    for (int blk = 0; blk < nblk; ++blk){
      const int c0 = 3 + 12*blk, g0 = c0 >> 2;
      LGKM_N(0, F1); BARRIER_; ISSUEB4(g0+2);
      WAITA_N(12, A0r); DS8(c0+1, F0); MFMA16(A0r, F1); ISSUEA(c0+3, A0r);
      WAITA_N(12, A1r); DS8(c0+2, F1); LGKM_N(8, F0); MFMA16(A1r, F0); ISSUEA(c0+4,  A1r);
      WAITA_N(12, A2r); DS8(c0+3, F0); LGKM_N(8, F1); MFMA16(A2r, F1); ISSUEA(c0+5,  A2r);
      WAITA_N(8,  A0r); DS8(c0+4, F1); LGKM_N(8, F0); MFMA16(A0r, F0); ISSUEA(c0+6,  A0r);
      LGKM_N(0, F1); BARRIER_; ISSUEB4(g0+3);
      WAITA_N(12, A1r); DS8(c0+5, F0); MFMA16(A1r, F1); ISSUEA(c0+7, A1r);
      WAITA_N(12, A2r); DS8(c0+6, F1); LGKM_N(8, F0); MFMA16(A2r, F0); ISSUEA(c0+8,  A2r);
      WAITA_N(12, A0r); DS8(c0+7, F0); LGKM_N(8, F1); MFMA16(A0r, F1); ISSUEA(c0+9,  A0r);
      WAITA_N(8,  A1r); DS8(c0+8, F1); LGKM_N(8, F0); MFMA16(A1r, F0); ISSUEA(c0+10, A1r);
      LGKM_N(0, F1); BARRIER_; ISSUEB4(g0+4);
      WAITA_N(12, A2r); DS8(c0+9, F0); MFMA16(A2r, F1); ISSUEA(c0+11, A2r);
      WAITA_N(12, A0r); DS8(c0+10, F1); LGKM_N(8, F0); MFMA16(A0r, F0); ISSUEA(c0+12, A0r);
      WAITA_N(12, A1r); DS8(c0+11, F0); LGKM_N(8, F1); MFMA16(A1r, F1); ISSUEA(c0+13, A1r);
      WAITA_N(8,  A2r); DS8(c0+12, F1); LGKM_N(8, F0); MFMA16(A2r, F0); ISSUEA(c0+14, A2r);
    }

    LGKM_N(0, F1); BARRIER_;
    WAITA_N(8, A0r); DS8(ncmax-4, F0); MFMA16(A0r, F1); ISSUEA(ncmax-2, A0r);
    WAITA_N(8, A1r); DS8(ncmax-3, F1); LGKM_N(8, F0); MFMA16(A1r, F0); ISSUEA(ncmax-1, A1r);
    WAITA_N(8, A2r); DS8(ncmax-2, F0); LGKM_N(8, F1); MFMA16(A2r, F1);
    WAITA_N(4, A0r); DS8(ncmax-1, F1); LGKM_N(8, F0); MFMA16(A0r, F0);
    WAITA_N(0, A1r);                   LGKM_N(0, F1); MFMA16(A1r, F1);

#undef ISSUEB4
#undef BARRIER_
#undef MFMA16
#undef LGKM_N
#undef DS8
#undef WAITA_N
#undef ISSUEA

    // ---- epilogue: LSTM cell, C in registers, h written frag-packed ----
    const int gl = lane&3, sbase = lane&60;
    #pragma unroll
    for (int tj = 0; tj < 4; tj++){
      const int ncol = col0 + tj*16 + c15;
      const int unit = ncol >> 2;
      const float bn = use_gt ? bgt[tj] : bngt[tj];
      #pragma unroll
      for (int ti = 0; ti < 2; ti++){
        f32x4 v = acc[ti][tj];
        #pragma unroll
        for (int r = 0; r < 4; r++){
          float x   = v[r] + bn;
          float act = (gl == 2) ? tanh_fast(x) : sigf(x);   // lane's own gate only
          float iv = __shfl(act, sbase);
          float fv = __shfl(act, sbase + 1);
          float gv = __shfl(act, sbase + 2);
          float ov = __shfl(act, sbase + 3);
          float cn = fmaf(fv, creg[tj*8 + ti*4 + r], iv*gv);
          creg[tj*8 + ti*4 + r] = cn;
          float hn = ov * tanh_fast(cn);
          int m = m_w + ti*16 + quad*4 + r;
          if (gl == 1) hout[fpo(m, unit, 16)] = (f16)hn;
        }
      }
    }

    // ---- publish + prefetch next step's weights ----
    __threadfence();                 // release: h stores visible device-wide
    __syncthreads();                 // all waves' stores fenced; all LDS reads done
    if (threadIdx.x == 0)
      __hip_atomic_fetch_add(&arrive[layer*32], 1u, __ATOMIC_RELAXED,
                             __HIP_MEMORY_SCOPE_AGENT);
    if (t + 1 < TT) prefetchB01();   // in flight across the next sync window
  }
}

// ================= final output GEMM (frag-packed A=H2A, B=Wd; LDS-free) =================
__global__ __launch_bounds__(256) void k_final(const char* __restrict__ ws,
                                               const float* __restrict__ bd,
                                               float* __restrict__ dout)
{
  const int w = threadIdx.x >> 6, lane = threadIdx.x & 63;
  const int n0 = blockIdx.x*128, m0 = blockIdx.y*128;
  const char* Bf = ws + OFF_WD;
  const int m_w = m0 + (w>>1)*64, n_w = n0 + (w&1)*64;
  const char* Af = ws + OFF_H2ALL + (size_t)(m_w >> 8)*BB*HID*2;   // t-matrix base
  const int vl = lane*16;

  f32x4 acc[4][4];
  f32x4 zero = {0.f, 0.f, 0.f, 0.f};
  #pragma unroll
  for (int i = 0; i < 4; i++)
    #pragma unroll
    for (int j = 0; j < 4; j++) acc[i][j] = zero;

  for (int c = 0; c < 16; c++){
    f16x8 av[4][2], bv[4][2];
    #pragma unroll
    for (int ti = 0; ti < 4; ti++){
      const char* b = Af + (((size_t)(((m_w & 255) >> 4) + ti)*16 + c) << 11) + vl;
      av[ti][0] = *(const f16x8*)(b);
      av[ti][1] = *(const f16x8*)(b + 1024);
    }
    #pragma unroll
    for (int tj = 0; tj < 4; tj++){
      const char* b = Bf + (((size_t)((n_w >> 4) + tj)*16 + c) << 11) + vl;
      bv[tj][0] = *(const f16x8*)(b);
      bv[tj][1] = *(const f16x8*)(b + 1024);
    }
    #pragma unroll
    for (int kw = 0; kw < 2; kw++)
      #pragma unroll
      for (int ti = 0; ti < 4; ti++)
        #pragma unroll
        for (int tj = 0; tj < 4; tj++)
          acc[ti][tj] = mfma8(av[ti][kw], bv[tj][kw], acc[ti][tj]);
  }

  const int quad = lane>>4, c15 = lane&15;
  #pragma unroll
  for (int tj = 0; tj < 4; tj++){
    int o = n_w + tj*16 + c15;
    bool valid = (o < 227);
    float bn = valid ? bd[o] : 0.f;
    #pragma unroll
    for (int ti = 0; ti < 4; ti++){
      f32x4 v = acc[ti][tj];
      #pragma unroll
      for (int r = 0; r < 4; r++){
        int m = m_w + ti*16 + quad*4 + r;
        if (valid){
          int tt = m >> 8, b = m & 255;
          dout[(size_t)b*22700 + (size_t)tt*227 + o] = v[r] + bn;
        }
      }
    }
  }
}

// ================= host =================
extern "C" void kernel_launch(void* const* d_in, const int* in_sizes, int n_in,
                              void* d_out, int out_size, void* d_ws, size_t ws_size,
                              hipStream_t stream)
{
  (void)in_sizes; (void)n_in; (void)out_size; (void)ws_size;
  const float* seq  = (const float*)d_in[0];
  const float* Wih1 = (const float*)d_in[1];
  const float* Whh1 = (const float*)d_in[2];
  const float* bih1 = (const float*)d_in[3];
  const float* bhh1 = (const float*)d_in[4];
  const float* Wih2 = (const float*)d_in[5];
  const float* Whh2 = (const float*)d_in[6];
  const float* bih2 = (const float*)d_in[7];
  const float* bhh2 = (const float*)d_in[8];
  const float* Wih3 = (const float*)d_in[9];
  const float* Whh3 = (const float*)d_in[10];
  const float* bih3 = (const float*)d_in[11];
  const float* bhh3 = (const float*)d_in[12];
  const float* Wd   = (const float*)d_in[13];
  const float* bd   = (const float*)d_in[14];
  char* ws = (char*)d_ws;

  (void)hipMemsetAsync(ws + OFF_C,    0, (size_t)3*BB*HID*4, stream);   // arrive flags
  (void)hipMemsetAsync(ws + OFF_HBUF, 0, (size_t)2*BB*HID*2, stream);
  (void)hipMemsetAsync(ws + OFF_H2Z,  0, (size_t)BB*HID*2,   stream);

  k_pack5   <<<dim3(2048, 5), dim3(256), 0, stream>>>(Whh1, Wih2, Whh2, Wih3, Whh3, ws);
  k_packwih1<<<dim3(4096),    dim3(256), 0, stream>>>(Wih1, ws);
  k_packwd  <<<dim3(128),     dim3(256), 0, stream>>>(Wd, ws);
  k_packwdt <<<dim3(1024),    dim3(256), 0, stream>>>(Wd, ws);
  k_xpad    <<<dim3(3200),    dim3(256), 0, stream>>>(seq, ws);
  k_bias    <<<dim3(16),      dim3(256), 0, stream>>>(bih1, bhh1, bih2, bhh2, bih3, bhh3, Wih1, bd, ws);
  k_w1d     <<<dim3(8, 32),   dim3(256), 0, stream>>>(ws);

  char* wsp = ws;
  void* kargs[] = { (void*)&wsp };
  (void)hipLaunchCooperativeKernel((const void*)k_steps, dim3(64, 3), dim3(512), kargs, 0, stream);

  k_final<<<dim3(2, 200), dim3(256), 0, stream>>>((const char*)ws, bd, (float*)d_out);
}

// Round 11
// 2854.961 us; speedup vs baseline: 3.2825x; 3.2825x over previous
//
#include <hip/hip_runtime.h>
#include <cstdint>

typedef _Float16 f16;
typedef _Float16 f16x8 __attribute__((ext_vector_type(8)));
typedef float    f32x4 __attribute__((ext_vector_type(4)));

#define DINL __device__ __forceinline__

static constexpr int HID = 1024;
static constexpr int NG  = 4096;   // 4*HID gate count
static constexpr int BB  = 256;    // batch
static constexpr int TT  = 100;    // seq len
static constexpr int KX  = 256;    // padded input-feature K (227 -> 256)
static constexpr size_t MSZ = (size_t)NG * HID;   // halves per packed [4096][1024] mat

// ---- workspace layout (bytes). total ~124 MiB ----
static constexpr size_t OFF_PACKW5 = 0;
static constexpr size_t OFF_W1D    = OFF_PACKW5 + 5*MSZ*2;
static constexpr size_t OFF_WIH1   = OFF_W1D   + MSZ*2;
static constexpr size_t OFF_WD     = OFF_WIH1  + (size_t)NG*KX*2;
static constexpr size_t OFF_XPAD   = OFF_WD    + (size_t)256*HID*2;
static constexpr size_t OFF_BIAS   = OFF_XPAD  + (size_t)TT*BB*KX*2;
static constexpr size_t OFF_C      = OFF_BIAS  + (size_t)4*NG*4;
static constexpr size_t OFF_HBUF   = OFF_C     + (size_t)3*BB*HID*4;
static constexpr size_t OFF_H2Z    = OFF_HBUF  + (size_t)4*BB*HID*2;
static constexpr size_t OFF_H2ALL  = OFF_H2Z   + (size_t)BB*HID*2;
// WdT scratch (frag-packed [1024 n][256 k] f16) lives at OFF_H2ALL until k_w1d consumes it.

// Fragment-packed layout ("frag order") for a [n][k] matrix, NCH = K/64:
// unit (nt=n>>4, c=k>>6, kw=(k>>5)&1) = 1KB; lane l=(n&15)|(quad<<4) holds the
// 8 f16 at k = c*64+kw*32+quad*8+e. A wave's fragment = ONE 1KB load at base+lane*16.
DINL size_t fpo(int n, int k, int NCH){
  return ((((size_t)(n>>4)*NCH + (k>>6))*2 + ((k>>5)&1)) << 9)
       + ((size_t)((n&15) | (((k>>3)&3) << 4)) << 3) + (k&7);
}

DINL void async16(void* lds, const void* g){
  auto lp = reinterpret_cast<__attribute__((address_space(3))) unsigned int*>(
      reinterpret_cast<uintptr_t>(lds));
  auto gp = reinterpret_cast<const __attribute__((address_space(1))) unsigned int*>(
      reinterpret_cast<uintptr_t>(g));
  __builtin_amdgcn_global_load_lds(gp, lp, 16, 0, 0);
}

// LDS read via inline asm: invisible to the compiler's LDS-DMA waitcnt pass.
DINL f16x8 ldsr128(unsigned a){
  f16x8 r;
  asm volatile("ds_read_b128 %0, %1" : "=v"(r) : "v"(a));
  return r;
}

// coalesced global->VGPR fragment load, 64-bit vaddr form
DINL f16x8 gload(const void* addr){
  f16x8 r;
  asm volatile("global_load_dwordx4 %0, %1, off"
    : "=v"(r) : "v"(addr));
  return r;
}

DINL f32x4 mfma8(f16x8 a, f16x8 b, f32x4 c){
  return __builtin_amdgcn_mfma_f32_16x16x32_f16(a, b, c, 0, 0, 0);
}

DINL float sigf(float x){
  x = fminf(fmaxf(x, -30.f), 30.f);
  return __fdividef(1.f, 1.f + __expf(-x));
}
DINL float tanh_fast(float x){
  x = fminf(fmaxf(x, -15.f), 15.f);
  float t = __expf(2.f*x);
  return __fdividef(t - 1.f, t + 1.f);
}

// ================= prep kernels (all weights + activations FRAG-PACKED) =================

__global__ void k_pack5(const float* W0, const float* W1, const float* W2,
                        const float* W3, const float* W4, char* ws)
{
  f16* dst = (f16*)(ws + OFF_PACKW5);
  const int mat = blockIdx.y;
  const float* src = mat==0?W0 : mat==1?W1 : mat==2?W2 : mat==3?W3 : W4;
  int tid = blockIdx.x*256 + threadIdx.x;
  int n = tid >> 7, kc = tid & 127;
  int r = ((n&3) << 10) + (n >> 2);
  const float* s = src + (size_t)r*HID + kc*8;
  f16x8 o;
  #pragma unroll
  for (int i = 0; i < 8; i++) o[i] = (f16)s[i];
  int nt = n >> 4, cch = kc >> 3, kw = (kc >> 2) & 1, quad = kc & 3;
  size_t off = ((((size_t)nt*16 + cch)*2 + kw) << 9)
             + ((size_t)((n&15) | (quad<<4)) << 3);
  *(f16x8*)(dst + (size_t)mat*MSZ + off) = o;
}

// vectorized: one f16x8 frag-slot store per thread (8 consecutive k share one slot)
__global__ void k_packwih1(const float* __restrict__ Wih1, char* ws){
  f16* dst = (f16*)(ws + OFF_WIH1);           // frag-packed, NCH=4
  int idx = blockIdx.x*256 + threadIdx.x;     // 512 blocks -> 131072 = 4096 n x 32 k8
  int n = idx >> 5, k8 = idx & 31;
  int r = ((n&3) << 10) + (n >> 2);
  f16x8 v;
  #pragma unroll
  for (int e = 0; e < 8; e++){
    int k = k8*8 + e;
    v[e] = (k < 227) ? (f16)Wih1[(size_t)r*227 + k] : (f16)0.f;
  }
  *(f16x8*)(dst + fpo(n, k8*8, 4)) = v;
}

__global__ void k_packwd(const float* __restrict__ Wd, char* ws){
  f16* dst = (f16*)(ws + OFF_WD);             // frag-packed [256 o][1024 h], NCH=16
  int idx = blockIdx.x*256 + threadIdx.x;
  int o = idx >> 7, k8 = idx & 127;
  f16x8 v;
  #pragma unroll
  for (int e = 0; e < 8; e++)
    v[e] = (o < 227) ? (f16)Wd[(size_t)o*HID + k8*8 + e] : (f16)0.f;
  size_t off = ((((size_t)(o>>4)*16 + (k8>>3))*2 + ((k8>>2)&1)) << 9)
             + ((size_t)((o&15) | ((k8&3)<<4)) << 3);
  *(f16x8*)(dst + off) = v;
}

__global__ void k_packwdt(const float* __restrict__ Wd, char* ws){
  f16* dst = (f16*)(ws + OFF_H2ALL);          // WdT frag-packed, n=h, k=o, NCH=4
  int h = blockIdx.x, o = threadIdx.x;
  dst[fpo(h, o, 4)] = (o < 227) ? (f16)Wd[(size_t)o*HID + h] : (f16)0.f;
}

__global__ void k_xpad(const float* __restrict__ seq, char* ws){
  f16* dst = (f16*)(ws + OFF_XPAD);           // per-t frag-packed [256 b][256 k], NCH=4
  int idx = blockIdx.x*256 + threadIdx.x;
  int t = idx >> 13, rem = idx & 8191, b = rem >> 5, k8 = rem & 31;
  f16x8 v;
  #pragma unroll
  for (int e = 0; e < 8; e++){
    int k = k8*8 + e;
    v[e] = (k < 227) ? (f16)seq[(size_t)b*22700 + (size_t)t*227 + k] : (f16)0.f;
  }
  size_t off = ((((size_t)(b>>4)*4 + (k8>>3))*2 + ((k8>>2)&1)) << 9)
             + ((size_t)((b&15) | ((k8&3)<<4)) << 3);
  *(f16x8*)(dst + (size_t)t*BB*KX + off) = v;
}

__global__ void k_bias(const float* bih1, const float* bhh1, const float* bih2, const float* bhh2,
                       const float* bih3, const float* bhh3, const float* Wih1, const float* bd,
                       char* ws)
{
  int n = blockIdx.x*256 + threadIdx.x;
  if (n >= NG) return;
  int r = ((n&3) << 10) + (n >> 2);
  float* b = (float*)(ws + OFF_BIAS);
  float bf = bih1[r] + bhh1[r];
  float s = 0.f;
  for (int o = 0; o < 227; o++) s += Wih1[(size_t)r*227 + o] * bd[o];
  b[n]        = bf;
  b[NG + n]   = bf + s;
  b[2*NG + n] = bih2[r] + bhh2[r];
  b[3*NG + n] = bih3[r] + bhh3[r];
}

// W1D = WIH1(frag,NCH=4) @ WdT(frag,NCH=4) -> frag-packed (NCH=16) output. LDS-free.
__global__ __launch_bounds__(256) void k_w1d(char* ws)
{
  const int w = threadIdx.x >> 6, lane = threadIdx.x & 63;
  const int n0 = blockIdx.x*128, m0 = blockIdx.y*128;
  const f16* Af = (const f16*)(ws + OFF_WIH1);
  const f16* Bf = (const f16*)(ws + OFF_H2ALL);
  f16* W1D = (f16*)(ws + OFF_W1D);
  const int m_w = m0 + (w>>1)*64, n_w = n0 + (w&1)*64;
  const int vl = lane*8;

  f32x4 acc[4][4];
  f32x4 zero = {0.f, 0.f, 0.f, 0.f};
  #pragma unroll
  for (int i = 0; i < 4; i++)
    #pragma unroll
    for (int j = 0; j < 4; j++) acc[i][j] = zero;

  for (int c = 0; c < 4; c++){
    f16x8 av[4][2], bv[4][2];
    #pragma unroll
    for (int ti = 0; ti < 4; ti++)
      #pragma unroll
      for (int kw = 0; kw < 2; kw++)
        av[ti][kw] = *(const f16x8*)(Af + ((((size_t)((m_w>>4)+ti)*4 + c)*2 + kw) << 9) + vl);
    #pragma unroll
    for (int tj = 0; tj < 4; tj++)
      #pragma unroll
      for (int kw = 0; kw < 2; kw++)
        bv[tj][kw] = *(const f16x8*)(Bf + ((((size_t)((n_w>>4)+tj)*4 + c)*2 + kw) << 9) + vl);
    #pragma unroll
    for (int kw = 0; kw < 2; kw++)
      #pragma unroll
      for (int ti = 0; ti < 4; ti++)
        #pragma unroll
        for (int tj = 0; tj < 4; tj++)
          acc[ti][tj] = mfma8(av[ti][kw], bv[tj][kw], acc[ti][tj]);
  }

  const int quad = lane>>4, c15 = lane&15;
  #pragma unroll
  for (int tj = 0; tj < 4; tj++){
    int col = n_w + tj*16 + c15;
    #pragma unroll
    for (int ti = 0; ti < 4; ti++){
      f32x4 v = acc[ti][tj];
      #pragma unroll
      for (int r = 0; r < 4; r++){
        int m = m_w + ti*16 + quad*4 + r;
        W1D[fpo(m, col, 16)] = (f16)v[r];
      }
    }
  }
}

// ================= recurrent step kernel (round-8 structure, proven) =================
// grid (64 ntiles, 3 layers), 512 threads = 8 waves (2/SIMD). Tm=256 x Tn=64, BK=64.
//   B (weights): LDS ring 8 slabs x 8KB (frag-packed, linear lane*16); fragment
//     ds_reads READ-AHEAD ONE CHUNK into 2 register banks (lgkmcnt(8) per iter).
//     Barriers at c%4==3; lgkmcnt(0) drained BEFORE each barrier.
//   A (h-state): frag-packed global -> coalesced 1KB gloads, 3 register banks,
//     prefetch distance 3.
__global__ __launch_bounds__(512, 2) void k_step(char* __restrict__ ws, int t, int use_gt)
{
  __shared__ __align__(16) char lds[65536];
  const int w = threadIdx.x >> 6, lane = threadIdx.x & 63;
  const int col0 = blockIdx.x*64, layer = blockIdx.y;

  const f16* packW = (const f16*)(ws + OFF_PACKW5);
  const f16* W1D   = (const f16*)(ws + OFF_W1D);
  const f16* WIH1  = (const f16*)(ws + OFF_WIH1);
  const f16* XP    = (const f16*)(ws + OFF_XPAD) + (size_t)t*BB*KX;
  const float* biasb = (const float*)(ws + OFF_BIAS);
  float* Cst = (float*)(ws + OFF_C);
  f16* HB  = (f16*)(ws + OFF_HBUF);
  f16* H2Z = (f16*)(ws + OFF_H2Z);
  f16* H2A = (f16*)(ws + OFF_H2ALL);

  const int pr = t & 1, pw = pr ^ 1;
  const f16* h0p = HB + (size_t)(pr*2 + 0)*BB*HID;
  const f16* h1p = HB + (size_t)(pr*2 + 1)*BB*HID;
  const f16* h2p = (t == 0) ? H2Z : (H2A + (size_t)(t-1)*BB*HID);

  const f16 *A0, *A1, *B0, *B1; int K1;
  const float* biasp; f16* hout; float* cptr;
  if (layer == 0){
    A0 = h0p; B0 = packW;
    if (use_gt){ A1 = XP;  B1 = WIH1; K1 = KX;  biasp = biasb; }
    else       { A1 = h2p; B1 = W1D;  K1 = HID; biasp = biasb + NG; }
    hout = HB + (size_t)(pw*2 + 0)*BB*HID; cptr = Cst;
  } else if (layer == 1){
    A0 = h0p; B0 = packW + MSZ;  A1 = h1p; B1 = packW + 2*MSZ; K1 = HID;
    biasp = biasb + 2*NG; hout = HB + (size_t)(pw*2 + 1)*BB*HID; cptr = Cst + (size_t)BB*HID;
  } else {
    A0 = h1p; B0 = packW + 3*MSZ; A1 = h2p; B1 = packW + 4*MSZ; K1 = HID;
    biasp = biasb + 3*NG; hout = H2A + (size_t)t*BB*HID; cptr = Cst + (size_t)2*BB*HID;
  }
  const int ncmax = 16 + (K1 >> 6);   // 32, or 20 for layer0/gt
  const int NCH1  = K1 >> 6;          // 16 or 4

  const int m_w = w*32, c15 = lane&15, quad = lane>>4;
  const unsigned vl16 = (unsigned)(lane * 16);
  const unsigned ldsBase = (unsigned)(uintptr_t)lds;

  // A per-lane unit bases (byte) per row-tile ti; NCH(A0)=16, NCH(A1)=NCH1
  const char* a0b[2]; const char* a1b[2];
  #pragma unroll
  for (int ti = 0; ti < 2; ti++){
    a0b[ti] = (const char*)A0 + (size_t)(2*w + ti)*16*2048   + (size_t)lane*16;
    a1b[ti] = (const char*)A1 + (size_t)(2*w + ti)*NCH1*2048 + (size_t)lane*16;
  }
  // B unit base for THIS wave's piece (tj=w>>1, kw=w&1), per-lane global src
  const char* b0u = (const char*)B0 + (size_t)((col0>>4) + (w>>1))*16*2048   + (size_t)(w&1)*1024 + (size_t)lane*16;
  const char* b1u = (const char*)B1 + (size_t)((col0>>4) + (w>>1))*NCH1*2048 + (size_t)(w&1)*1024 + (size_t)lane*16;

  auto issueB = [&](int ci){
    const char* s = (ci < 16) ? (b0u + (size_t)ci*2048) : (b1u + (size_t)(ci-16)*2048);
    async16(lds + (ci & 7)*8192 + w*1024, s);
  };
  auto abase = [&](int ci, int ti)->const char*{
    return (ci < 16) ? (a0b[ti] + (size_t)ci*2048) : (a1b[ti] + (size_t)(ci-16)*2048);
  };

  f32x4 acc[2][4];
  f32x4 zero = {0.f, 0.f, 0.f, 0.f};
  #pragma unroll
  for (int i = 0; i < 2; i++)
    #pragma unroll
    for (int j = 0; j < 4; j++) acc[i][j] = zero;

  f16x8 A0r[4], A1r[4], A2r[4];   // three A banks (bank = chunk%3), idx = ti*2+kw
  f16x8 F0[8], F1[8];             // two B frag banks (bank = chunk&1), idx = tj*2+kw

#define ISSUEA(CI, AK)                                           \
  { const char* _b0 = abase((CI), 0);                            \
    const char* _b1 = abase((CI), 1);                            \
    AK[0] = gload(_b0);                                          \
    AK[1] = gload(_b0 + 1024);                                   \
    AK[2] = gload(_b1);                                          \
    AK[3] = gload(_b1 + 1024); }

#define WAITA_N(LIT, AK) asm volatile("s_waitcnt vmcnt(" #LIT ")" \
    : "+v"(AK[0]), "+v"(AK[1]), "+v"(AK[2]), "+v"(AK[3]))

#define DS8(CI, F)                                               \
  { const unsigned _sb = ldsBase + (unsigned)(((CI)&7)*8192) + vl16; \
    F[0] = ldsr128(_sb);         F[1] = ldsr128(_sb + 1024u);    \
    F[2] = ldsr128(_sb + 2048u); F[3] = ldsr128(_sb + 3072u);    \
    F[4] = ldsr128(_sb + 4096u); F[5] = ldsr128(_sb + 5120u);    \
    F[6] = ldsr128(_sb + 6144u); F[7] = ldsr128(_sb + 7168u); }

#define LGKM_N(LIT, F) asm volatile("s_waitcnt lgkmcnt(" #LIT ")" \
    : "+v"(F[0]), "+v"(F[1]), "+v"(F[2]), "+v"(F[3]),            \
      "+v"(F[4]), "+v"(F[5]), "+v"(F[6]), "+v"(F[7]))

#define MFMA16(AK, F)                                            \
    acc[0][0] = mfma8(AK[0], F[0], acc[0][0]);                   \
    acc[0][1] = mfma8(AK[0], F[2], acc[0][1]);                   \
    acc[0][2] = mfma8(AK[0], F[4], acc[0][2]);                   \
    acc[0][3] = mfma8(AK[0], F[6], acc[0][3]);                   \
    acc[1][0] = mfma8(AK[2], F[0], acc[1][0]);                   \
    acc[1][1] = mfma8(AK[2], F[2], acc[1][1]);                   \
    acc[1][2] = mfma8(AK[2], F[4], acc[1][2]);                   \
    acc[1][3] = mfma8(AK[2], F[6], acc[1][3]);                   \
    acc[0][0] = mfma8(AK[1], F[1], acc[0][0]);                   \
    acc[0][1] = mfma8(AK[1], F[3], acc[0][1]);                   \
    acc[0][2] = mfma8(AK[1], F[5], acc[0][2]);                   \
    acc[0][3] = mfma8(AK[1], F[7], acc[0][3]);                   \
    acc[1][0] = mfma8(AK[3], F[1], acc[1][0]);                   \
    acc[1][1] = mfma8(AK[3], F[3], acc[1][1]);                   \
    acc[1][2] = mfma8(AK[3], F[5], acc[1][2]);                   \
    acc[1][3] = mfma8(AK[3], F[7], acc[1][3]);

#define BARRIER_ { __builtin_amdgcn_s_barrier(); __builtin_amdgcn_sched_barrier(0); }
#define ISSUEB4(G) { const int _cb = 4*(G); issueB(_cb); issueB(_cb+1); issueB(_cb+2); issueB(_cb+3); }

  // ---- prologue: B groups 0,1 + A(0..2); publish; frag-read chunk 0 ----
  ISSUEB4(0); ISSUEB4(1);
  ISSUEA(0, A0r); ISSUEA(1, A1r); ISSUEA(2, A2r);
  asm volatile("s_waitcnt vmcnt(16)" ::: "memory");   // own Bg0 done (Bg1,A0..A2 newer)
  BARRIER_;
  DS8(0, F0);

  // ---- peel c = 0,1,2 ----
  WAITA_N(8, A0r); DS8(1, F1); LGKM_N(8, F0); MFMA16(A0r, F0); ISSUEA(3, A0r);
  WAITA_N(8, A1r); DS8(2, F0); LGKM_N(8, F1); MFMA16(A1r, F1); ISSUEA(4, A1r);
  WAITA_N(8, A2r); DS8(3, F1); LGKM_N(8, F0); MFMA16(A2r, F0); ISSUEA(5, A2r);

  // ---- 12-iter phase blocks: c = 3+12*blk .. 14+12*blk ----
  const int nblk = (ncmax - 8) / 12;          // 1 (ncmax=20) or 2 (ncmax=32)
  for (int blk = 0; blk < nblk; ++blk){
    const int c0 = 3 + 12*blk, g0 = c0 >> 2;
    LGKM_N(0, F1); BARRIER_; ISSUEB4(g0+2);
    WAITA_N(12, A0r); DS8(c0+1, F0); MFMA16(A0r, F1); ISSUEA(c0+3, A0r);
    WAITA_N(12, A1r); DS8(c0+2, F1); LGKM_N(8, F0); MFMA16(A1r, F0); ISSUEA(c0+4,  A1r);
    WAITA_N(12, A2r); DS8(c0+3, F0); LGKM_N(8, F1); MFMA16(A2r, F1); ISSUEA(c0+5,  A2r);
    WAITA_N(8,  A0r); DS8(c0+4, F1); LGKM_N(8, F0); MFMA16(A0r, F0); ISSUEA(c0+6,  A0r);
    LGKM_N(0, F1); BARRIER_; ISSUEB4(g0+3);
    WAITA_N(12, A1r); DS8(c0+5, F0); MFMA16(A1r, F1); ISSUEA(c0+7, A1r);
    WAITA_N(12, A2r); DS8(c0+6, F1); LGKM_N(8, F0); MFMA16(A2r, F0); ISSUEA(c0+8,  A2r);
    WAITA_N(12, A0r); DS8(c0+7, F0); LGKM_N(8, F1); MFMA16(A0r, F1); ISSUEA(c0+9,  A0r);
    WAITA_N(8,  A1r); DS8(c0+8, F1); LGKM_N(8, F0); MFMA16(A1r, F0); ISSUEA(c0+10, A1r);
    LGKM_N(0, F1); BARRIER_; ISSUEB4(g0+4);
    WAITA_N(12, A2r); DS8(c0+9, F0); MFMA16(A2r, F1); ISSUEA(c0+11, A2r);
    WAITA_N(12, A0r); DS8(c0+10, F1); LGKM_N(8, F0); MFMA16(A0r, F0); ISSUEA(c0+12, A0r);
    WAITA_N(12, A1r); DS8(c0+11, F0); LGKM_N(8, F1); MFMA16(A1r, F1); ISSUEA(c0+13, A1r);
    WAITA_N(8,  A2r); DS8(c0+12, F1); LGKM_N(8, F0); MFMA16(A2r, F0); ISSUEA(c0+14, A2r);
  }

  // ---- tail: c = ncmax-5 .. ncmax-1 ----
  LGKM_N(0, F1); BARRIER_;
  WAITA_N(8, A0r); DS8(ncmax-4, F0); MFMA16(A0r, F1); ISSUEA(ncmax-2, A0r);
  WAITA_N(8, A1r); DS8(ncmax-3, F1); LGKM_N(8, F0); MFMA16(A1r, F0); ISSUEA(ncmax-1, A1r);
  WAITA_N(8, A2r); DS8(ncmax-2, F0); LGKM_N(8, F1); MFMA16(A2r, F1);
  WAITA_N(4, A0r); DS8(ncmax-1, F1); LGKM_N(8, F0); MFMA16(A0r, F0);
  WAITA_N(0, A1r);                   LGKM_N(0, F1); MFMA16(A1r, F1);

#undef ISSUEB4
#undef BARRIER_
#undef MFMA16
#undef LGKM_N
#undef DS8
#undef WAITA_N
#undef ISSUEA

  // ---- fused LSTM cell epilogue; h written FRAG-PACKED ----
  const int gl = lane&3, sbase = lane&60;
  #pragma unroll
  for (int tj = 0; tj < 4; tj++){
    const int ncol = col0 + tj*16 + c15;
    const int unit = ncol >> 2;
    const float bn = biasp[ncol];
    float cp[8];
    #pragma unroll
    for (int ti = 0; ti < 2; ti++)
      #pragma unroll
      for (int r = 0; r < 4; r++)
        cp[ti*4 + r] = cptr[(size_t)(m_w + ti*16 + quad*4 + r)*HID + unit];
    #pragma unroll
    for (int ti = 0; ti < 2; ti++){
      f32x4 v = acc[ti][tj];
      #pragma unroll
      for (int r = 0; r < 4; r++){
        float x   = v[r] + bn;
        float act = (gl == 2) ? tanh_fast(x) : sigf(x);   // lane's own gate only
        float iv = __shfl(act, sbase);
        float fv = __shfl(act, sbase + 1);
        float gv = __shfl(act, sbase + 2);
        float ov = __shfl(act, sbase + 3);
        float cn = fmaf(fv, cp[ti*4 + r], iv*gv);
        float hn = ov * tanh_fast(cn);
        int m = m_w + ti*16 + quad*4 + r;
        if (gl == 0)      cptr[(size_t)m*HID + unit] = cn;
        else if (gl == 1) hout[fpo(m, unit, 16)] = (f16)hn;
      }
    }
  }
}

// ================= final output GEMM (frag-packed A=H2A, B=Wd; LDS-free) =================
__global__ __launch_bounds__(256) void k_final(const char* __restrict__ ws,
                                               const float* __restrict__ bd,
                                               float* __restrict__ dout)
{
  const int w = threadIdx.x >> 6, lane = threadIdx.x & 63;
  const int n0 = blockIdx.x*128, m0 = blockIdx.y*128;
  const char* Bf = ws + OFF_WD;
  const int m_w = m0 + (w>>1)*64, n_w = n0 + (w&1)*64;
  const char* Af = ws + OFF_H2ALL + (size_t)(m_w >> 8)*BB*HID*2;   // t-matrix base
  const int vl = lane*16;

  f32x4 acc[4][4];
  f32x4 zero = {0.f, 0.f, 0.f, 0.f};
  #pragma unroll
  for (int i = 0; i < 4; i++)
    #pragma unroll
    for (int j = 0; j < 4; j++) acc[i][j] = zero;

  for (int c = 0; c < 16; c++){
    f16x8 av[4][2], bv[4][2];
    #pragma unroll
    for (int ti = 0; ti < 4; ti++){
      const char* b = Af + (((size_t)(((m_w & 255) >> 4) + ti)*16 + c) << 11) + vl;
      av[ti][0] = *(const f16x8*)(b);
      av[ti][1] = *(const f16x8*)(b + 1024);
    }
    #pragma unroll
    for (int tj = 0; tj < 4; tj++){
      const char* b = Bf + (((size_t)((n_w >> 4) + tj)*16 + c) << 11) + vl;
      bv[tj][0] = *(const f16x8*)(b);
      bv[tj][1] = *(const f16x8*)(b + 1024);
    }
    #pragma unroll
    for (int kw = 0; kw < 2; kw++)
      #pragma unroll
      for (int ti = 0; ti < 4; ti++)
        #pragma unroll
        for (int tj = 0; tj < 4; tj++)
          acc[ti][tj] = mfma8(av[ti][kw], bv[tj][kw], acc[ti][tj]);
  }

  const int quad = lane>>4, c15 = lane&15;
  #pragma unroll
  for (int tj = 0; tj < 4; tj++){
    int o = n_w + tj*16 + c15;
    bool valid = (o < 227);
    float bn = valid ? bd[o] : 0.f;
    #pragma unroll
    for (int ti = 0; ti < 4; ti++){
      f32x4 v = acc[ti][tj];
      #pragma unroll
      for (int r = 0; r < 4; r++){
        int m = m_w + ti*16 + quad*4 + r;
        if (valid){
          int tt = m >> 8, b = m & 255;
          dout[(size_t)b*22700 + (size_t)tt*227 + o] = v[r] + bn;
        }
      }
    }
  }
}

// ================= host =================
extern "C" void kernel_launch(void* const* d_in, const int* in_sizes, int n_in,
                              void* d_out, int out_size, void* d_ws, size_t ws_size,
                              hipStream_t stream)
{
  (void)in_sizes; (void)n_in; (void)out_size; (void)ws_size;
  const float* seq  = (const float*)d_in[0];
  const float* Wih1 = (const float*)d_in[1];
  const float* Whh1 = (const float*)d_in[2];
  const float* bih1 = (const float*)d_in[3];
  const float* bhh1 = (const float*)d_in[4];
  const float* Wih2 = (const float*)d_in[5];
  const float* Whh2 = (const float*)d_in[6];
  const float* bih2 = (const float*)d_in[7];
  const float* bhh2 = (const float*)d_in[8];
  const float* Wih3 = (const float*)d_in[9];
  const float* Whh3 = (const float*)d_in[10];
  const float* bih3 = (const float*)d_in[11];
  const float* bhh3 = (const float*)d_in[12];
  const float* Wd   = (const float*)d_in[13];
  const float* bd   = (const float*)d_in[14];
  char* ws = (char*)d_ws;

  (void)hipMemsetAsync(ws + OFF_C,    0, (size_t)3*BB*HID*4, stream);
  (void)hipMemsetAsync(ws + OFF_HBUF, 0, (size_t)2*BB*HID*2, stream);
  (void)hipMemsetAsync(ws + OFF_H2Z,  0, (size_t)BB*HID*2,   stream);

  k_pack5   <<<dim3(2048, 5), dim3(256), 0, stream>>>(Whh1, Wih2, Whh2, Wih3, Whh3, ws);
  k_packwih1<<<dim3(512),     dim3(256), 0, stream>>>(Wih1, ws);
  k_packwd  <<<dim3(128),     dim3(256), 0, stream>>>(Wd, ws);
  k_packwdt <<<dim3(1024),    dim3(256), 0, stream>>>(Wd, ws);
  k_xpad    <<<dim3(3200),    dim3(256), 0, stream>>>(seq, ws);
  k_bias    <<<dim3(16),      dim3(256), 0, stream>>>(bih1, bhh1, bih2, bhh2, bih3, bhh3, Wih1, bd, ws);
  k_w1d     <<<dim3(8, 32),   dim3(256), 0, stream>>>(ws);

  for (int t = 0; t < TT; t++){
    int ug = ((t % 10) < 5) ? 1 : 0;
    k_step<<<dim3(64, 3), dim3(512), 0, stream>>>(ws, t, ug);
  }

  k_final<<<dim3(2, 200), dim3(256), 0, stream>>>((const char*)ws, bd, (float*)d_out);
}